// Round 11
// baseline (441.769 us; speedup 1.0000x reference)
//
#include <hip/hip_runtime.h>
#include <hip/hip_bf16.h>

// GAT (3 layers) + MLP head. N=50000, E=800000 (+N self loops), D=128, H=256, C=6.
// R7: 348.0 (banked best) | R5: t_agg=38x3 | R8: t_gat=9.2x3 | R10: g=1.4us/launch
// => boundaries ~19us; ~187us unaccounted in {prologue,mlp,cold-effects,harness}.
// R11 probe: re-run the full CSR chain+prep (idempotent as a unit) and mlp once.
// dur - 348 - 11(boundaries) = t_prologue(warm) + t_mlp(warm). Banked best untouched.

typedef _Float16 h4 __attribute__((ext_vector_type(4)));
typedef _Float16 half8 __attribute__((ext_vector_type(8)));
typedef float f32x4 __attribute__((ext_vector_type(4)));

#define LDA 136    // padded fp16 row stride for MFMA staging (gat kernel)
#define DCAP 128   // max degree for the LDS fast path (Poisson(17): P(>128)~0)
#define DPAD 129   // LDS row stride (odd => groups hit different banks)

__device__ inline int src_chunk(int s) {
    int c = s >> 14;             // 16384 rows * 256B = 4MB of hh per chunk
    return (c > 3) ? 3 : c;
}

__global__ __launch_bounds__(256) void k_zero(int* __restrict__ p, int n) {
    int i = blockIdx.x * 256 + threadIdx.x;
    if (i < n) p[i] = 0;
}

// per-(dst, src-chunk) histogram; rank = arrival order within (dst,chunk)
__global__ __launch_bounds__(256) void k_hist(const int* __restrict__ ei, int* __restrict__ deg2,
                                              int* __restrict__ rank, int E_, int N_) {
    int e = blockIdx.x * 256 + threadIdx.x;
    int total = E_ + N_;
    if (e >= total) return;
    int s, d;
    if (e < E_) { s = ei[e]; d = ei[E_ + e]; }
    else        { s = e - E_; d = e - E_; }
    rank[e] = atomicAdd(&deg2[d * 4 + src_chunk(s)], 1);
}

__device__ inline int block_incl_scan(int v, int* wsum) {
    int lane = threadIdx.x & 63, wid = threadIdx.x >> 6;
    #pragma unroll
    for (int d = 1; d < 64; d <<= 1) {
        int t = __shfl_up(v, d);
        if (lane >= d) v += t;
    }
    if (lane == 63) wsum[wid] = v;
    __syncthreads();
    if (wid == 0 && lane < 4) {
        int s = wsum[lane];
        #pragma unroll
        for (int d = 1; d < 4; d <<= 1) {
            int t = __shfl_up(s, d);
            if (lane >= d) s += t;
        }
        wsum[lane] = s;
    }
    __syncthreads();
    if (wid > 0) v += wsum[wid - 1];
    return v;
}

__global__ __launch_bounds__(256) void k_bsum(const int* __restrict__ deg2, int* __restrict__ bsum, int n) {
    __shared__ int wsum[4];
    int i = blockIdx.x * 256 + threadIdx.x;
    int v = 0;
    if (i < n) v = deg2[i * 4] + deg2[i * 4 + 1] + deg2[i * 4 + 2] + deg2[i * 4 + 3];
    int lane = threadIdx.x & 63, wid = threadIdx.x >> 6;
    #pragma unroll
    for (int d = 32; d > 0; d >>= 1) v += __shfl_down(v, d);
    if (lane == 0) wsum[wid] = v;
    __syncthreads();
    if (threadIdx.x == 0) bsum[blockIdx.x] = wsum[0] + wsum[1] + wsum[2] + wsum[3];
}

__global__ __launch_bounds__(256) void k_scanb(int* __restrict__ bsum, int nb) {
    __shared__ int wsum[4];
    int i = threadIdx.x;
    int orig = (i < nb) ? bsum[i] : 0;
    int v = block_incl_scan(orig, wsum);
    if (i < nb) bsum[i] = v - orig;
}

// off[] (per dst, for aggregate) + off2[] (per dst x chunk, for scatter)
__global__ __launch_bounds__(256) void k_off(const int* __restrict__ deg2, const int* __restrict__ bsum,
                                             int* __restrict__ off, int* __restrict__ off2, int n) {
    __shared__ int wsum[4];
    int i = blockIdx.x * 256 + threadIdx.x;
    int d0 = 0, d1 = 0, d2 = 0, d3 = 0;
    if (i < n) {
        d0 = deg2[i * 4]; d1 = deg2[i * 4 + 1]; d2 = deg2[i * 4 + 2]; d3 = deg2[i * 4 + 3];
    }
    int orig = d0 + d1 + d2 + d3;
    int v = block_incl_scan(orig, wsum);
    int base = bsum[blockIdx.x];
    if (i < n) {
        int o = base + v - orig;
        off[i] = o;
        off2[i * 4]     = o;
        off2[i * 4 + 1] = o + d0;
        off2[i * 4 + 2] = o + d0 + d1;
        off2[i * 4 + 3] = o + d0 + d1 + d2;
    }
    if (i == n - 1) off[n] = base + v;
}

__global__ __launch_bounds__(256) void k_scatter(const int* __restrict__ ei, const int* __restrict__ off2,
                                                 const int* __restrict__ rank, int* __restrict__ csrc,
                                                 int E_, int N_) {
    int e = blockIdx.x * 256 + threadIdx.x;
    int total = E_ + N_;
    if (e >= total) return;
    int s, d;
    if (e < E_) { s = ei[e]; d = ei[E_ + e]; }
    else        { s = e - E_; d = e - E_; }
    csrc[off2[d * 4 + src_chunk(s)] + rank[e]] = s;
}

// fused prep: x->fp16, W0..W2 transpose->fp16, Wm1 transpose->fp16
__global__ __launch_bounds__(256) void k_prep(const float* __restrict__ x, _Float16* __restrict__ xh,
        const float* __restrict__ W0, const float* __restrict__ W1, const float* __restrict__ W2,
        _Float16* __restrict__ Wt3, const float* __restrict__ Wm1, _Float16* __restrict__ Wm1t, int n4) {
    int i = blockIdx.x * 256 + threadIdx.x;
    if (i < n4) {
        float4 v = ((const float4*)x)[i];
        h4 o;
        o.x = (_Float16)v.x; o.y = (_Float16)v.y; o.z = (_Float16)v.z; o.w = (_Float16)v.w;
        ((h4*)xh)[i] = o;
        return;
    }
    int t = i - n4;
    if (t < 3 * 16384) {
        int seg = t >> 14;
        int j = t & 16383;
        const float* W = (seg == 0) ? W0 : (seg == 1) ? W1 : W2;
        int nn = j >> 7, k = j & 127;
        Wt3[t] = (_Float16)W[k * 128 + nn];
        return;
    }
    t -= 3 * 16384;
    if (t < 32768) {
        int nn = t >> 7, k = t & 127;
        Wm1t[t] = (_Float16)Wm1[k * 256 + nn];
    }
}

// Layer GEMM via MFMA: hh[M x 128](fp16) = A16[M x 128] @ W + fused alpha dots.
__global__ __launch_bounds__(256, 3) void k_mfma_gat(const _Float16* __restrict__ A16,
        const _Float16* __restrict__ Wt, const float* __restrict__ asrc, const float* __restrict__ adst,
        _Float16* __restrict__ hh, float* __restrict__ avs, float* __restrict__ avd, int M) {
    __shared__ _Float16 As[64 * LDA];
    __shared__ _Float16 Bs[128 * LDA];
    int tid = threadIdx.x;
    int bm = blockIdx.x * 64;
    #pragma unroll
    for (int i = 0; i < 4; ++i) {
        int idx = i * 256 + tid;
        int row = idx >> 4, c16 = idx & 15;
        int gr = bm + row;
        uint4 v = make_uint4(0u, 0u, 0u, 0u);
        if (gr < M) v = *(const uint4*)(A16 + (size_t)gr * 128 + c16 * 8);
        *(uint4*)&As[row * LDA + c16 * 8] = v;
    }
    #pragma unroll
    for (int i = 0; i < 8; ++i) {
        int idx = i * 256 + tid;
        int row = idx >> 4, c16 = idx & 15;
        *(uint4*)&Bs[row * LDA + c16 * 8] = *(const uint4*)(Wt + (size_t)row * 128 + c16 * 8);
    }
    __syncthreads();
    int w = tid >> 6, l = tid & 63;
    int quad = l >> 4, cl = l & 15;
    f32x4 acc[8] = {};
    const _Float16* ap = &As[(w * 16 + cl) * LDA + quad * 8];
    #pragma unroll
    for (int kt = 0; kt < 4; ++kt) {
        half8 a = *(const half8*)(ap + kt * 32);
        #pragma unroll
        for (int ct = 0; ct < 8; ++ct) {
            half8 b = *(const half8*)&Bs[(ct * 16 + cl) * LDA + kt * 32 + quad * 8];
            acc[ct] = __builtin_amdgcn_mfma_f32_16x16x32_f16(a, b, acc[ct], 0, 0, 0);
        }
    }
    float sa[8], da[8];
    #pragma unroll
    for (int ct = 0; ct < 8; ++ct) { sa[ct] = asrc[ct * 16 + cl]; da[ct] = adst[ct * 16 + cl]; }
    #pragma unroll
    for (int r = 0; r < 4; ++r) {
        int row = bm + w * 16 + quad * 4 + r;
        bool ok = row < M;
        float ps = 0.f, pd = 0.f;
        #pragma unroll
        for (int ct = 0; ct < 8; ++ct) {
            float v = acc[ct][r];
            if (ok) hh[(size_t)row * 128 + ct * 16 + cl] = (_Float16)v;
            ps += v * sa[ct];
            pd += v * da[ct];
        }
        #pragma unroll
        for (int msk = 1; msk <= 8; msk <<= 1) { ps += __shfl_xor(ps, msk); pd += __shfl_xor(pd, msk); }
        if (cl == 0 && ok) { avs[row] = ps; avd[row] = pd; }
    }
}

// Fused MLP, acc[8]-only: out[M x 6] = relu(A16 @ Wm1 + bm1) @ Wm2 + bm2.
__global__ __launch_bounds__(256) void k_mfma_mlp(const _Float16* __restrict__ A16,
        const _Float16* __restrict__ Wt, const float* __restrict__ bias,
        const float* __restrict__ W2, const float* __restrict__ b2,
        float* __restrict__ out, int M) {
    __shared__ float W2s[256 * 6];
    __shared__ float bss[256];
    __shared__ float comb[4][16][6];
    int tid = threadIdx.x;
    #pragma unroll
    for (int i = 0; i < 6; ++i) W2s[i * 256 + tid] = W2[i * 256 + tid];
    bss[tid] = bias[tid];
    __syncthreads();
    int w = tid >> 6, l = tid & 63;
    int quad = l >> 4, cl = l & 15;
    int rg = w >> 1;             // row-group 0/1
    int ch = w & 1;              // col-half 0/1
    int bm = blockIdx.x * 32 + rg * 16;
    int arow = bm + cl;
    int arc = (arow < M) ? arow : (M - 1);   // clamp; combine discards OOB rows
    const _Float16* ap = A16 + (size_t)arc * 128 + quad * 8;
    f32x4 acc[8];
    #pragma unroll
    for (int i = 0; i < 8; ++i) acc[i] = (f32x4){0.f, 0.f, 0.f, 0.f};
    #pragma unroll
    for (int kt = 0; kt < 4; ++kt) {
        half8 av = *(const half8*)(ap + kt * 32);
        const _Float16* bp = Wt + (size_t)(ch * 128 + cl) * 128 + kt * 32 + quad * 8;
        #pragma unroll
        for (int ct = 0; ct < 8; ++ct) {
            half8 bv = *(const half8*)(bp + (size_t)ct * 16 * 128);
            acc[ct] = __builtin_amdgcn_mfma_f32_16x16x32_f16(av, bv, acc[ct], 0, 0, 0);
        }
    }
    float pc[4][6] = {};
    #pragma unroll
    for (int ct = 0; ct < 8; ++ct) {
        int col = ch * 128 + ct * 16 + cl;
        float bb = bss[col];
        float w0 = W2s[col * 6 + 0], w1 = W2s[col * 6 + 1], w2v = W2s[col * 6 + 2];
        float w3 = W2s[col * 6 + 3], w4 = W2s[col * 6 + 4], w5 = W2s[col * 6 + 5];
        #pragma unroll
        for (int r = 0; r < 4; ++r) {
            float v = fmaxf(acc[ct][r] + bb, 0.f);
            pc[r][0] += v * w0; pc[r][1] += v * w1; pc[r][2] += v * w2v;
            pc[r][3] += v * w3; pc[r][4] += v * w4; pc[r][5] += v * w5;
        }
    }
    #pragma unroll
    for (int r = 0; r < 4; ++r) {
        #pragma unroll
        for (int msk = 1; msk <= 8; msk <<= 1) {
            #pragma unroll
            for (int c = 0; c < 6; ++c) pc[r][c] += __shfl_xor(pc[r][c], msk);
        }
        if (cl == 0) {
            #pragma unroll
            for (int c = 0; c < 6; ++c) comb[w][quad * 4 + r][c] = pc[r][c];
        }
    }
    __syncthreads();
    // combine halves + store: 192 entries (2 row-groups x 16 rows x 6 cols)
    if (tid < 192) {
        int rgg = tid / 96;
        int rem = tid % 96;
        int rr = rem / 6, c = rem % 6;
        int row = blockIdx.x * 32 + rgg * 16 + rr;
        if (row < M)
            out[(size_t)row * 6 + c] = comb[rgg * 2][rr][c] + comb[rgg * 2 + 1][rr][c] + b2[c];
    }
}

// Group-owned aggregation: one 16-lane group per dst node (4 nodes/wave, 16/block).
__global__ __launch_bounds__(256) void k_aggregate(const _Float16* __restrict__ hh, const int* __restrict__ off,
                                                   const int* __restrict__ csrc, const float* __restrict__ avs,
                                                   const float* __restrict__ avd, const float* __restrict__ bias,
                                                   _Float16* __restrict__ outh, int n) {
    __shared__ float ew[16][DPAD];
    __shared__ int   si[16][DPAD];
    int tid = threadIdx.x;
    int row = tid >> 4;   // group slot 0..15
    int gl  = tid & 15;
    int w = blockIdx.x * 16 + row;
    if (w >= n) return;
    int beg = off[w], end = off[w + 1];
    int deg = end - beg;
    float adn = avd[w];
    float accf[8] = {};
    float ssum;

    if (deg <= DCAP) {
        // pass 1: scores -> LDS, group max, exp -> LDS, group sum
        float m = -1e30f;
        for (int k = gl; k < deg; k += 16) {
            int s = csrc[beg + k];
            float sc = avs[s] + adn;
            sc = (sc < 0.f) ? 0.2f * sc : sc;
            si[row][k] = s;
            ew[row][k] = sc;
            m = fmaxf(m, sc);
        }
        #pragma unroll
        for (int d = 1; d < 16; d <<= 1) m = fmaxf(m, __shfl_xor(m, d));
        float ss = 0.f;
        for (int k = gl; k < deg; k += 16) {
            float e = __expf(ew[row][k] - m);
            ew[row][k] = e;
            ss += e;
        }
        #pragma unroll
        for (int d = 1; d < 16; d <<= 1) ss += __shfl_xor(ss, d);
        ssum = ss;
        // pass 2: serial edges, 8-deep unroll; s/e broadcast from LDS
        int j = 0;
        for (; j + 7 < deg; j += 8) {
            int s0 = si[row][j],     s1 = si[row][j + 1], s2 = si[row][j + 2], s3 = si[row][j + 3];
            int s4 = si[row][j + 4], s5 = si[row][j + 5], s6 = si[row][j + 6], s7 = si[row][j + 7];
            half8 v0 = *((const half8*)(hh + (size_t)s0 * 128) + gl);
            half8 v1 = *((const half8*)(hh + (size_t)s1 * 128) + gl);
            half8 v2 = *((const half8*)(hh + (size_t)s2 * 128) + gl);
            half8 v3 = *((const half8*)(hh + (size_t)s3 * 128) + gl);
            half8 v4 = *((const half8*)(hh + (size_t)s4 * 128) + gl);
            half8 v5 = *((const half8*)(hh + (size_t)s5 * 128) + gl);
            half8 v6 = *((const half8*)(hh + (size_t)s6 * 128) + gl);
            half8 v7 = *((const half8*)(hh + (size_t)s7 * 128) + gl);
            float e0 = ew[row][j],     e1 = ew[row][j + 1], e2 = ew[row][j + 2], e3 = ew[row][j + 3];
            float e4 = ew[row][j + 4], e5 = ew[row][j + 5], e6 = ew[row][j + 6], e7 = ew[row][j + 7];
            #pragma unroll
            for (int f = 0; f < 8; ++f)
                accf[f] += ((e0 * (float)v0[f] + e1 * (float)v1[f])
                          + (e2 * (float)v2[f] + e3 * (float)v3[f]))
                         + ((e4 * (float)v4[f] + e5 * (float)v5[f])
                          + (e6 * (float)v6[f] + e7 * (float)v7[f]));
        }
        for (; j < deg; ++j) {
            int s0 = si[row][j];
            float e0 = ew[row][j];
            half8 v0 = *((const half8*)(hh + (size_t)s0 * 128) + gl);
            #pragma unroll
            for (int f = 0; f < 8; ++f) accf[f] += e0 * (float)v0[f];
        }
    } else {
        // online fallback (deg > DCAP): redundant per-lane scalar softmax
        float m = -1e30f;
        for (int k = gl; k < deg; k += 16) {
            float sc = avs[csrc[beg + k]] + adn;
            sc = (sc < 0.f) ? 0.2f * sc : sc;
            m = fmaxf(m, sc);
        }
        #pragma unroll
        for (int d = 1; d < 16; d <<= 1) m = fmaxf(m, __shfl_xor(m, d));
        float ss = 0.f;
        for (int j = beg; j < end; ++j) {
            int s = csrc[j];
            float sc = avs[s] + adn;
            sc = (sc < 0.f) ? 0.2f * sc : sc;
            float e0 = __expf(sc - m);
            ss += e0;
            half8 v0 = *((const half8*)(hh + (size_t)s * 128) + gl);
            #pragma unroll
            for (int f = 0; f < 8; ++f) accf[f] += e0 * (float)v0[f];
        }
        ssum = ss;
    }
    float inv = 1.f / ssum;
    float4 b0 = ((const float4*)bias)[gl * 2];
    float4 b1 = ((const float4*)bias)[gl * 2 + 1];
    half8 o;
    o[0] = (_Float16)fmaxf(accf[0] * inv + b0.x, 0.f);
    o[1] = (_Float16)fmaxf(accf[1] * inv + b0.y, 0.f);
    o[2] = (_Float16)fmaxf(accf[2] * inv + b0.z, 0.f);
    o[3] = (_Float16)fmaxf(accf[3] * inv + b0.w, 0.f);
    o[4] = (_Float16)fmaxf(accf[4] * inv + b1.x, 0.f);
    o[5] = (_Float16)fmaxf(accf[5] * inv + b1.y, 0.f);
    o[6] = (_Float16)fmaxf(accf[6] * inv + b1.z, 0.f);
    o[7] = (_Float16)fmaxf(accf[7] * inv + b1.w, 0.f);
    *((half8*)(outh + (size_t)w * 128) + gl) = o;
}

extern "C" void kernel_launch(void* const* d_in, const int* in_sizes, int n_in,
                              void* d_out, int out_size, void* d_ws, size_t ws_size,
                              hipStream_t stream) {
    const float* x   = (const float*)d_in[0];
    const int*   ei  = (const int*)d_in[1];
    const float* W[3]    = {(const float*)d_in[2], (const float*)d_in[6], (const float*)d_in[10]};
    const float* bL[3]   = {(const float*)d_in[3], (const float*)d_in[7], (const float*)d_in[11]};
    const float* asr[3]  = {(const float*)d_in[4], (const float*)d_in[8], (const float*)d_in[12]};
    const float* ads[3]  = {(const float*)d_in[5], (const float*)d_in[9], (const float*)d_in[13]};
    const float* Wm1 = (const float*)d_in[14];
    const float* bm1 = (const float*)d_in[15];
    const float* Wm2 = (const float*)d_in[16];
    const float* bm2 = (const float*)d_in[17];
    float* out = (float*)d_out;

    const int N_ = in_sizes[0] / 128;
    const int E_ = in_sizes[1] / 2;
    const int TOT = E_ + N_;
    const int NB = (N_ + 255) / 256;

    char* p = (char*)d_ws;
    auto alloc = [&](size_t bytes) { void* r = (void*)p; p += (bytes + 255) & ~(size_t)255; return r; };
    int*   deg2 = (int*)alloc((size_t)N_ * 4 * 4);
    int*   off  = (int*)alloc((size_t)(N_ + 1) * 4);
    int*   off2 = (int*)alloc((size_t)N_ * 4 * 4);
    int*   bsum = (int*)alloc((size_t)(NB + 1) * 4);
    int*   rank = (int*)alloc((size_t)TOT * 4);
    int*   csrc = (int*)alloc((size_t)TOT * 4);
    float* avs  = (float*)alloc((size_t)N_ * 4);
    float* avd  = (float*)alloc((size_t)N_ * 4);
    _Float16* Wt3  = (_Float16*)alloc(3 * 16384 * 2);
    _Float16* Wm1t = (_Float16*)alloc(32768 * 2);
    _Float16* xh   = (_Float16*)alloc((size_t)N_ * 128 * 2);
    _Float16* agg  = (_Float16*)alloc((size_t)N_ * 128 * 2);
    _Float16* hh   = (_Float16*)alloc((size_t)N_ * 128 * 2);

    int n4 = N_ * 32;
    int prep_items = n4 + 3 * 16384 + 32768;

    // ---- CSR build (chunk-ordered) + prep: R7 structure ----
    k_zero<<<(N_ * 4 + 255) / 256, 256, 0, stream>>>(deg2, N_ * 4);
    k_hist<<<(TOT + 255) / 256, 256, 0, stream>>>(ei, deg2, rank, E_, N_);
    k_bsum<<<NB, 256, 0, stream>>>(deg2, bsum, N_);
    k_scanb<<<1, 256, 0, stream>>>(bsum, NB);
    k_off<<<NB, 256, 0, stream>>>(deg2, bsum, off, off2, N_);
    k_scatter<<<(TOT + 255) / 256, 256, 0, stream>>>(ei, off2, rank, csrc, E_, N_);
    k_prep<<<(prep_items + 255) / 256, 256, 0, stream>>>(x, xh, W[0], W[1], W[2], Wt3, Wm1, Wm1t, n4);

    // ---- PROBE: re-run the whole chain (idempotent as a unit) ----
    k_zero<<<(N_ * 4 + 255) / 256, 256, 0, stream>>>(deg2, N_ * 4);
    k_hist<<<(TOT + 255) / 256, 256, 0, stream>>>(ei, deg2, rank, E_, N_);
    k_bsum<<<NB, 256, 0, stream>>>(deg2, bsum, N_);
    k_scanb<<<1, 256, 0, stream>>>(bsum, NB);
    k_off<<<NB, 256, 0, stream>>>(deg2, bsum, off, off2, N_);
    k_scatter<<<(TOT + 255) / 256, 256, 0, stream>>>(ei, off2, rank, csrc, E_, N_);
    k_prep<<<(prep_items + 255) / 256, 256, 0, stream>>>(x, xh, W[0], W[1], W[2], Wt3, Wm1, Wm1t, n4);

    const int agg_blocks = (N_ + 15) / 16;
    const int gat_blocks = (N_ + 63) / 64;

    // ---- 3 GAT layers ----
    const _Float16* cur_in = xh;
    for (int l = 0; l < 3; ++l) {
        k_mfma_gat<<<gat_blocks, 256, 0, stream>>>(cur_in, Wt3 + l * 16384, asr[l], ads[l],
                                                   hh, avs, avd, N_);
        k_aggregate<<<agg_blocks, 256, 0, stream>>>(hh, off, csrc, avs, avd, bL[l], agg, N_);
        cur_in = agg;
    }

    // ---- fused MLP head (+ idempotent duplicate probe) ----
    k_mfma_mlp<<<(N_ + 31) / 32, 256, 0, stream>>>(agg, Wm1t, bm1, Wm2, bm2, out, N_);
    k_mfma_mlp<<<(N_ + 31) / 32, 256, 0, stream>>>(agg, Wm1t, bm1, Wm2, bm2, out, N_);
}

// Round 13
// 344.916 us; speedup vs baseline: 1.2808x; 1.2808x over previous
//
#include <hip/hip_runtime.h>
#include <hip/hip_bf16.h>

// GAT (3 layers) + MLP head. N=50000, E=800000 (+N self loops), D=128, H=256, C=6.
// Ledger (all measured): agg 3x38 | gat 3x9.2 | prologue ~68 | mlp ~15 |
// boundaries 14x1.4 | cold/harness residual ~104 (reset fills wipe L2+L3).
// R12: prologue cleanup. (a) k_zero folded into k_prep => k_zp (R9-verified
// safe half); (b) k_scanb folded into k_off: each block prefix-sums
// bsum[0..b) directly (<=196 ints, L2-broadcast) — removes the 1-block scan
// that idled 255/256 CUs. 14 -> 12 launches. hist/scatter/gat/agg/mlp
// byte-identical to banked R7 (348.0us).
// R13: identical resubmit — R12 hit a broker-side container failure (same
// signature as R0-R2, which cleared without kernel change).

typedef _Float16 h4 __attribute__((ext_vector_type(4)));
typedef _Float16 half8 __attribute__((ext_vector_type(8)));
typedef float f32x4 __attribute__((ext_vector_type(4)));

#define LDA 136    // padded fp16 row stride for MFMA staging (gat kernel)
#define DCAP 128   // max degree for the LDS fast path (Poisson(17): P(>128)~0)
#define DPAD 129   // LDS row stride (odd => groups hit different banks)

__device__ inline int src_chunk(int s) {
    int c = s >> 14;             // 16384 rows * 256B = 4MB of hh per chunk
    return (c > 3) ? 3 : c;
}

// fused zero(deg2) + prep (x->fp16, W0..W2 T->fp16, Wm1 T->fp16); independent work
__global__ __launch_bounds__(256) void k_zp(int* __restrict__ deg2, int nz,
        const float* __restrict__ x, _Float16* __restrict__ xh,
        const float* __restrict__ W0, const float* __restrict__ W1, const float* __restrict__ W2,
        _Float16* __restrict__ Wt3, const float* __restrict__ Wm1, _Float16* __restrict__ Wm1t, int n4) {
    int i = blockIdx.x * 256 + threadIdx.x;
    if (i < nz) { deg2[i] = 0; return; }
    int t = i - nz;
    if (t < n4) {
        float4 v = ((const float4*)x)[t];
        h4 o;
        o.x = (_Float16)v.x; o.y = (_Float16)v.y; o.z = (_Float16)v.z; o.w = (_Float16)v.w;
        ((h4*)xh)[t] = o;
        return;
    }
    t -= n4;
    if (t < 3 * 16384) {
        int seg = t >> 14;
        int j = t & 16383;
        const float* W = (seg == 0) ? W0 : (seg == 1) ? W1 : W2;
        int nn = j >> 7, k = j & 127;
        Wt3[t] = (_Float16)W[k * 128 + nn];
        return;
    }
    t -= 3 * 16384;
    if (t < 32768) {
        int nn = t >> 7, k = t & 127;
        Wm1t[t] = (_Float16)Wm1[k * 256 + nn];
    }
}

// per-(dst, src-chunk) histogram; rank = arrival order within (dst,chunk)
__global__ __launch_bounds__(256) void k_hist(const int* __restrict__ ei, int* __restrict__ deg2,
                                              int* __restrict__ rank, int E_, int N_) {
    int e = blockIdx.x * 256 + threadIdx.x;
    int total = E_ + N_;
    if (e >= total) return;
    int s, d;
    if (e < E_) { s = ei[e]; d = ei[E_ + e]; }
    else        { s = e - E_; d = e - E_; }
    rank[e] = atomicAdd(&deg2[d * 4 + src_chunk(s)], 1);
}

__device__ inline int block_incl_scan(int v, int* wsum) {
    int lane = threadIdx.x & 63, wid = threadIdx.x >> 6;
    #pragma unroll
    for (int d = 1; d < 64; d <<= 1) {
        int t = __shfl_up(v, d);
        if (lane >= d) v += t;
    }
    if (lane == 63) wsum[wid] = v;
    __syncthreads();
    if (wid == 0 && lane < 4) {
        int s = wsum[lane];
        #pragma unroll
        for (int d = 1; d < 4; d <<= 1) {
            int t = __shfl_up(s, d);
            if (lane >= d) s += t;
        }
        wsum[lane] = s;
    }
    __syncthreads();
    if (wid > 0) v += wsum[wid - 1];
    return v;
}

__global__ __launch_bounds__(256) void k_bsum(const int* __restrict__ deg2, int* __restrict__ bsum, int n) {
    __shared__ int wsum[4];
    int i = blockIdx.x * 256 + threadIdx.x;
    int v = 0;
    if (i < n) v = deg2[i * 4] + deg2[i * 4 + 1] + deg2[i * 4 + 2] + deg2[i * 4 + 3];
    int lane = threadIdx.x & 63, wid = threadIdx.x >> 6;
    #pragma unroll
    for (int d = 32; d > 0; d >>= 1) v += __shfl_down(v, d);
    if (lane == 0) wsum[wid] = v;
    __syncthreads();
    if (threadIdx.x == 0) bsum[blockIdx.x] = wsum[0] + wsum[1] + wsum[2] + wsum[3];
}

// off[] + off2[]; base computed in-kernel: sum of bsum[0..b) (tiny, L2-broadcast)
__global__ __launch_bounds__(256) void k_off(const int* __restrict__ deg2, const int* __restrict__ bsum,
                                             int* __restrict__ off, int* __restrict__ off2, int n) {
    __shared__ int rsum[4];
    __shared__ int wsum[4];
    int tid = threadIdx.x;
    int b = blockIdx.x;
    int acc = 0;
    for (int i = tid; i < b; i += 256) acc += bsum[i];
    int lane = tid & 63, wid = tid >> 6;
    #pragma unroll
    for (int d = 32; d > 0; d >>= 1) acc += __shfl_xor(acc, d);
    if (lane == 0) rsum[wid] = acc;
    __syncthreads();
    int base = rsum[0] + rsum[1] + rsum[2] + rsum[3];
    int i = b * 256 + tid;
    int d0 = 0, d1 = 0, d2 = 0, d3 = 0;
    if (i < n) {
        d0 = deg2[i * 4]; d1 = deg2[i * 4 + 1]; d2 = deg2[i * 4 + 2]; d3 = deg2[i * 4 + 3];
    }
    int orig = d0 + d1 + d2 + d3;
    int v = block_incl_scan(orig, wsum);
    if (i < n) {
        int o = base + v - orig;
        off[i] = o;
        off2[i * 4]     = o;
        off2[i * 4 + 1] = o + d0;
        off2[i * 4 + 2] = o + d0 + d1;
        off2[i * 4 + 3] = o + d0 + d1 + d2;
    }
    if (i == n - 1) off[n] = base + v;
}

__global__ __launch_bounds__(256) void k_scatter(const int* __restrict__ ei, const int* __restrict__ off2,
                                                 const int* __restrict__ rank, int* __restrict__ csrc,
                                                 int E_, int N_) {
    int e = blockIdx.x * 256 + threadIdx.x;
    int total = E_ + N_;
    if (e >= total) return;
    int s, d;
    if (e < E_) { s = ei[e]; d = ei[E_ + e]; }
    else        { s = e - E_; d = e - E_; }
    csrc[off2[d * 4 + src_chunk(s)] + rank[e]] = s;
}

// Layer GEMM via MFMA: hh[M x 128](fp16) = A16[M x 128] @ W + fused alpha dots.
__global__ __launch_bounds__(256, 3) void k_mfma_gat(const _Float16* __restrict__ A16,
        const _Float16* __restrict__ Wt, const float* __restrict__ asrc, const float* __restrict__ adst,
        _Float16* __restrict__ hh, float* __restrict__ avs, float* __restrict__ avd, int M) {
    __shared__ _Float16 As[64 * LDA];
    __shared__ _Float16 Bs[128 * LDA];
    int tid = threadIdx.x;
    int bm = blockIdx.x * 64;
    #pragma unroll
    for (int i = 0; i < 4; ++i) {
        int idx = i * 256 + tid;
        int row = idx >> 4, c16 = idx & 15;
        int gr = bm + row;
        uint4 v = make_uint4(0u, 0u, 0u, 0u);
        if (gr < M) v = *(const uint4*)(A16 + (size_t)gr * 128 + c16 * 8);
        *(uint4*)&As[row * LDA + c16 * 8] = v;
    }
    #pragma unroll
    for (int i = 0; i < 8; ++i) {
        int idx = i * 256 + tid;
        int row = idx >> 4, c16 = idx & 15;
        *(uint4*)&Bs[row * LDA + c16 * 8] = *(const uint4*)(Wt + (size_t)row * 128 + c16 * 8);
    }
    __syncthreads();
    int w = tid >> 6, l = tid & 63;
    int quad = l >> 4, cl = l & 15;
    f32x4 acc[8] = {};
    const _Float16* ap = &As[(w * 16 + cl) * LDA + quad * 8];
    #pragma unroll
    for (int kt = 0; kt < 4; ++kt) {
        half8 a = *(const half8*)(ap + kt * 32);
        #pragma unroll
        for (int ct = 0; ct < 8; ++ct) {
            half8 b = *(const half8*)&Bs[(ct * 16 + cl) * LDA + kt * 32 + quad * 8];
            acc[ct] = __builtin_amdgcn_mfma_f32_16x16x32_f16(a, b, acc[ct], 0, 0, 0);
        }
    }
    float sa[8], da[8];
    #pragma unroll
    for (int ct = 0; ct < 8; ++ct) { sa[ct] = asrc[ct * 16 + cl]; da[ct] = adst[ct * 16 + cl]; }
    #pragma unroll
    for (int r = 0; r < 4; ++r) {
        int row = bm + w * 16 + quad * 4 + r;
        bool ok = row < M;
        float ps = 0.f, pd = 0.f;
        #pragma unroll
        for (int ct = 0; ct < 8; ++ct) {
            float v = acc[ct][r];
            if (ok) hh[(size_t)row * 128 + ct * 16 + cl] = (_Float16)v;
            ps += v * sa[ct];
            pd += v * da[ct];
        }
        #pragma unroll
        for (int msk = 1; msk <= 8; msk <<= 1) { ps += __shfl_xor(ps, msk); pd += __shfl_xor(pd, msk); }
        if (cl == 0 && ok) { avs[row] = ps; avd[row] = pd; }
    }
}

// Fused MLP, acc[8]-only: out[M x 6] = relu(A16 @ Wm1 + bm1) @ Wm2 + bm2.
__global__ __launch_bounds__(256) void k_mfma_mlp(const _Float16* __restrict__ A16,
        const _Float16* __restrict__ Wt, const float* __restrict__ bias,
        const float* __restrict__ W2, const float* __restrict__ b2,
        float* __restrict__ out, int M) {
    __shared__ float W2s[256 * 6];
    __shared__ float bss[256];
    __shared__ float comb[4][16][6];
    int tid = threadIdx.x;
    #pragma unroll
    for (int i = 0; i < 6; ++i) W2s[i * 256 + tid] = W2[i * 256 + tid];
    bss[tid] = bias[tid];
    __syncthreads();
    int w = tid >> 6, l = tid & 63;
    int quad = l >> 4, cl = l & 15;
    int rg = w >> 1;             // row-group 0/1
    int ch = w & 1;              // col-half 0/1
    int bm = blockIdx.x * 32 + rg * 16;
    int arow = bm + cl;
    int arc = (arow < M) ? arow : (M - 1);   // clamp; combine discards OOB rows
    const _Float16* ap = A16 + (size_t)arc * 128 + quad * 8;
    f32x4 acc[8];
    #pragma unroll
    for (int i = 0; i < 8; ++i) acc[i] = (f32x4){0.f, 0.f, 0.f, 0.f};
    #pragma unroll
    for (int kt = 0; kt < 4; ++kt) {
        half8 av = *(const half8*)(ap + kt * 32);
        const _Float16* bp = Wt + (size_t)(ch * 128 + cl) * 128 + kt * 32 + quad * 8;
        #pragma unroll
        for (int ct = 0; ct < 8; ++ct) {
            half8 bv = *(const half8*)(bp + (size_t)ct * 16 * 128);
            acc[ct] = __builtin_amdgcn_mfma_f32_16x16x32_f16(av, bv, acc[ct], 0, 0, 0);
        }
    }
    float pc[4][6] = {};
    #pragma unroll
    for (int ct = 0; ct < 8; ++ct) {
        int col = ch * 128 + ct * 16 + cl;
        float bb = bss[col];
        float w0 = W2s[col * 6 + 0], w1 = W2s[col * 6 + 1], w2v = W2s[col * 6 + 2];
        float w3 = W2s[col * 6 + 3], w4 = W2s[col * 6 + 4], w5 = W2s[col * 6 + 5];
        #pragma unroll
        for (int r = 0; r < 4; ++r) {
            float v = fmaxf(acc[ct][r] + bb, 0.f);
            pc[r][0] += v * w0; pc[r][1] += v * w1; pc[r][2] += v * w2v;
            pc[r][3] += v * w3; pc[r][4] += v * w4; pc[r][5] += v * w5;
        }
    }
    #pragma unroll
    for (int r = 0; r < 4; ++r) {
        #pragma unroll
        for (int msk = 1; msk <= 8; msk <<= 1) {
            #pragma unroll
            for (int c = 0; c < 6; ++c) pc[r][c] += __shfl_xor(pc[r][c], msk);
        }
        if (cl == 0) {
            #pragma unroll
            for (int c = 0; c < 6; ++c) comb[w][quad * 4 + r][c] = pc[r][c];
        }
    }
    __syncthreads();
    // combine halves + store: 192 entries (2 row-groups x 16 rows x 6 cols)
    if (tid < 192) {
        int rgg = tid / 96;
        int rem = tid % 96;
        int rr = rem / 6, c = rem % 6;
        int row = blockIdx.x * 32 + rgg * 16 + rr;
        if (row < M)
            out[(size_t)row * 6 + c] = comb[rgg * 2][rr][c] + comb[rgg * 2 + 1][rr][c] + b2[c];
    }
}

// Group-owned aggregation: one 16-lane group per dst node (4 nodes/wave, 16/block).
__global__ __launch_bounds__(256) void k_aggregate(const _Float16* __restrict__ hh, const int* __restrict__ off,
                                                   const int* __restrict__ csrc, const float* __restrict__ avs,
                                                   const float* __restrict__ avd, const float* __restrict__ bias,
                                                   _Float16* __restrict__ outh, int n) {
    __shared__ float ew[16][DPAD];
    __shared__ int   si[16][DPAD];
    int tid = threadIdx.x;
    int row = tid >> 4;   // group slot 0..15
    int gl  = tid & 15;
    int w = blockIdx.x * 16 + row;
    if (w >= n) return;
    int beg = off[w], end = off[w + 1];
    int deg = end - beg;
    float adn = avd[w];
    float accf[8] = {};
    float ssum;

    if (deg <= DCAP) {
        // pass 1: scores -> LDS, group max, exp -> LDS, group sum
        float m = -1e30f;
        for (int k = gl; k < deg; k += 16) {
            int s = csrc[beg + k];
            float sc = avs[s] + adn;
            sc = (sc < 0.f) ? 0.2f * sc : sc;
            si[row][k] = s;
            ew[row][k] = sc;
            m = fmaxf(m, sc);
        }
        #pragma unroll
        for (int d = 1; d < 16; d <<= 1) m = fmaxf(m, __shfl_xor(m, d));
        float ss = 0.f;
        for (int k = gl; k < deg; k += 16) {
            float e = __expf(ew[row][k] - m);
            ew[row][k] = e;
            ss += e;
        }
        #pragma unroll
        for (int d = 1; d < 16; d <<= 1) ss += __shfl_xor(ss, d);
        ssum = ss;
        // pass 2: serial edges, 8-deep unroll; s/e broadcast from LDS
        int j = 0;
        for (; j + 7 < deg; j += 8) {
            int s0 = si[row][j],     s1 = si[row][j + 1], s2 = si[row][j + 2], s3 = si[row][j + 3];
            int s4 = si[row][j + 4], s5 = si[row][j + 5], s6 = si[row][j + 6], s7 = si[row][j + 7];
            half8 v0 = *((const half8*)(hh + (size_t)s0 * 128) + gl);
            half8 v1 = *((const half8*)(hh + (size_t)s1 * 128) + gl);
            half8 v2 = *((const half8*)(hh + (size_t)s2 * 128) + gl);
            half8 v3 = *((const half8*)(hh + (size_t)s3 * 128) + gl);
            half8 v4 = *((const half8*)(hh + (size_t)s4 * 128) + gl);
            half8 v5 = *((const half8*)(hh + (size_t)s5 * 128) + gl);
            half8 v6 = *((const half8*)(hh + (size_t)s6 * 128) + gl);
            half8 v7 = *((const half8*)(hh + (size_t)s7 * 128) + gl);
            float e0 = ew[row][j],     e1 = ew[row][j + 1], e2 = ew[row][j + 2], e3 = ew[row][j + 3];
            float e4 = ew[row][j + 4], e5 = ew[row][j + 5], e6 = ew[row][j + 6], e7 = ew[row][j + 7];
            #pragma unroll
            for (int f = 0; f < 8; ++f)
                accf[f] += ((e0 * (float)v0[f] + e1 * (float)v1[f])
                          + (e2 * (float)v2[f] + e3 * (float)v3[f]))
                         + ((e4 * (float)v4[f] + e5 * (float)v5[f])
                          + (e6 * (float)v6[f] + e7 * (float)v7[f]));
        }
        for (; j < deg; ++j) {
            int s0 = si[row][j];
            float e0 = ew[row][j];
            half8 v0 = *((const half8*)(hh + (size_t)s0 * 128) + gl);
            #pragma unroll
            for (int f = 0; f < 8; ++f) accf[f] += e0 * (float)v0[f];
        }
    } else {
        // online fallback (deg > DCAP): redundant per-lane scalar softmax
        float m = -1e30f;
        for (int k = gl; k < deg; k += 16) {
            float sc = avs[csrc[beg + k]] + adn;
            sc = (sc < 0.f) ? 0.2f * sc : sc;
            m = fmaxf(m, sc);
        }
        #pragma unroll
        for (int d = 1; d < 16; d <<= 1) m = fmaxf(m, __shfl_xor(m, d));
        float ss = 0.f;
        for (int j = beg; j < end; ++j) {
            int s = csrc[j];
            float sc = avs[s] + adn;
            sc = (sc < 0.f) ? 0.2f * sc : sc;
            float e0 = __expf(sc - m);
            ss += e0;
            half8 v0 = *((const half8*)(hh + (size_t)s * 128) + gl);
            #pragma unroll
            for (int f = 0; f < 8; ++f) accf[f] += e0 * (float)v0[f];
        }
        ssum = ss;
    }
    float inv = 1.f / ssum;
    float4 b0 = ((const float4*)bias)[gl * 2];
    float4 b1 = ((const float4*)bias)[gl * 2 + 1];
    half8 o;
    o[0] = (_Float16)fmaxf(accf[0] * inv + b0.x, 0.f);
    o[1] = (_Float16)fmaxf(accf[1] * inv + b0.y, 0.f);
    o[2] = (_Float16)fmaxf(accf[2] * inv + b0.z, 0.f);
    o[3] = (_Float16)fmaxf(accf[3] * inv + b0.w, 0.f);
    o[4] = (_Float16)fmaxf(accf[4] * inv + b1.x, 0.f);
    o[5] = (_Float16)fmaxf(accf[5] * inv + b1.y, 0.f);
    o[6] = (_Float16)fmaxf(accf[6] * inv + b1.z, 0.f);
    o[7] = (_Float16)fmaxf(accf[7] * inv + b1.w, 0.f);
    *((half8*)(outh + (size_t)w * 128) + gl) = o;
}

extern "C" void kernel_launch(void* const* d_in, const int* in_sizes, int n_in,
                              void* d_out, int out_size, void* d_ws, size_t ws_size,
                              hipStream_t stream) {
    const float* x   = (const float*)d_in[0];
    const int*   ei  = (const int*)d_in[1];
    const float* W[3]    = {(const float*)d_in[2], (const float*)d_in[6], (const float*)d_in[10]};
    const float* bL[3]   = {(const float*)d_in[3], (const float*)d_in[7], (const float*)d_in[11]};
    const float* asr[3]  = {(const float*)d_in[4], (const float*)d_in[8], (const float*)d_in[12]};
    const float* ads[3]  = {(const float*)d_in[5], (const float*)d_in[9], (const float*)d_in[13]};
    const float* Wm1 = (const float*)d_in[14];
    const float* bm1 = (const float*)d_in[15];
    const float* Wm2 = (const float*)d_in[16];
    const float* bm2 = (const float*)d_in[17];
    float* out = (float*)d_out;

    const int N_ = in_sizes[0] / 128;
    const int E_ = in_sizes[1] / 2;
    const int TOT = E_ + N_;
    const int NB = (N_ + 255) / 256;

    char* p = (char*)d_ws;
    auto alloc = [&](size_t bytes) { void* r = (void*)p; p += (bytes + 255) & ~(size_t)255; return r; };
    int*   deg2 = (int*)alloc((size_t)N_ * 4 * 4);
    int*   off  = (int*)alloc((size_t)(N_ + 1) * 4);
    int*   off2 = (int*)alloc((size_t)N_ * 4 * 4);
    int*   bsum = (int*)alloc((size_t)(NB + 1) * 4);
    int*   rank = (int*)alloc((size_t)TOT * 4);
    int*   csrc = (int*)alloc((size_t)TOT * 4);
    float* avs  = (float*)alloc((size_t)N_ * 4);
    float* avd  = (float*)alloc((size_t)N_ * 4);
    _Float16* Wt3  = (_Float16*)alloc(3 * 16384 * 2);
    _Float16* Wm1t = (_Float16*)alloc(32768 * 2);
    _Float16* xh   = (_Float16*)alloc((size_t)N_ * 128 * 2);
    _Float16* agg  = (_Float16*)alloc((size_t)N_ * 128 * 2);
    _Float16* hh   = (_Float16*)alloc((size_t)N_ * 128 * 2);

    // ---- fused CSR build (chunk-ordered) + prep: 5 launches ----
    int nz = N_ * 4;
    int n4 = N_ * 32;
    int zp_items = nz + n4 + 3 * 16384 + 32768;
    k_zp<<<(zp_items + 255) / 256, 256, 0, stream>>>(deg2, nz, x, xh, W[0], W[1], W[2],
                                                     Wt3, Wm1, Wm1t, n4);
    k_hist<<<(TOT + 255) / 256, 256, 0, stream>>>(ei, deg2, rank, E_, N_);
    k_bsum<<<NB, 256, 0, stream>>>(deg2, bsum, N_);
    k_off<<<NB, 256, 0, stream>>>(deg2, bsum, off, off2, N_);
    k_scatter<<<(TOT + 255) / 256, 256, 0, stream>>>(ei, off2, rank, csrc, E_, N_);

    const int agg_blocks = (N_ + 15) / 16;
    const int gat_blocks = (N_ + 63) / 64;

    // ---- 3 GAT layers ----
    const _Float16* cur_in = xh;
    for (int l = 0; l < 3; ++l) {
        k_mfma_gat<<<gat_blocks, 256, 0, stream>>>(cur_in, Wt3 + l * 16384, asr[l], ads[l],
                                                   hh, avs, avd, N_);
        k_aggregate<<<agg_blocks, 256, 0, stream>>>(hh, off, csrc, avs, avd, bL[l], agg, N_);
        cur_in = agg;
    }

    // ---- fused MLP head ----
    k_mfma_mlp<<<(N_ + 31) / 32, 256, 0, stream>>>(agg, Wm1t, bm1, Wm2, bm2, out, N_);
}

// Round 14
// 336.471 us; speedup vs baseline: 1.3129x; 1.0251x over previous
//
#include <hip/hip_runtime.h>
#include <hip/hip_bf16.h>

// GAT (3 layers) + MLP head. N=50000, E=800000 (+N self loops), D=128, H=256, C=6.
// Ledger: agg 3x38 (=91% of 6.3TB/s achievable BW => at roofline) | prologue
// ~60 | gat 3x9.2 | boundaries ~17 | mlp 15 | cold/harness ~104.
// R13 (zp + scanb-fold): 344.9us, banked best.
// R14: k_hist has NO dependency on gat layer 1 (both only need k_zp outputs).
// Partition-fused k_gat_hist: blocks [0,gat_blocks) = gat1 (byte-identical
// body), blocks [gat_blocks,..) = hist (byte-identical body). Latency-bound
// hist hides under compute-bound gat1. 12 -> 11 launches.

typedef _Float16 h4 __attribute__((ext_vector_type(4)));
typedef _Float16 half8 __attribute__((ext_vector_type(8)));
typedef float f32x4 __attribute__((ext_vector_type(4)));

#define LDA 136    // padded fp16 row stride for MFMA staging (gat kernel)
#define DCAP 128   // max degree for the LDS fast path (Poisson(17): P(>128)~0)
#define DPAD 129   // LDS row stride (odd => groups hit different banks)

__device__ inline int src_chunk(int s) {
    int c = s >> 14;             // 16384 rows * 256B = 4MB of hh per chunk
    return (c > 3) ? 3 : c;
}

// fused zero(deg2) + prep (x->fp16, W0..W2 T->fp16, Wm1 T->fp16); independent work
__global__ __launch_bounds__(256) void k_zp(int* __restrict__ deg2, int nz,
        const float* __restrict__ x, _Float16* __restrict__ xh,
        const float* __restrict__ W0, const float* __restrict__ W1, const float* __restrict__ W2,
        _Float16* __restrict__ Wt3, const float* __restrict__ Wm1, _Float16* __restrict__ Wm1t, int n4) {
    int i = blockIdx.x * 256 + threadIdx.x;
    if (i < nz) { deg2[i] = 0; return; }
    int t = i - nz;
    if (t < n4) {
        float4 v = ((const float4*)x)[t];
        h4 o;
        o.x = (_Float16)v.x; o.y = (_Float16)v.y; o.z = (_Float16)v.z; o.w = (_Float16)v.w;
        ((h4*)xh)[t] = o;
        return;
    }
    t -= n4;
    if (t < 3 * 16384) {
        int seg = t >> 14;
        int j = t & 16383;
        const float* W = (seg == 0) ? W0 : (seg == 1) ? W1 : W2;
        int nn = j >> 7, k = j & 127;
        Wt3[t] = (_Float16)W[k * 128 + nn];
        return;
    }
    t -= 3 * 16384;
    if (t < 32768) {
        int nn = t >> 7, k = t & 127;
        Wm1t[t] = (_Float16)Wm1[k * 256 + nn];
    }
}

__device__ inline int block_incl_scan(int v, int* wsum) {
    int lane = threadIdx.x & 63, wid = threadIdx.x >> 6;
    #pragma unroll
    for (int d = 1; d < 64; d <<= 1) {
        int t = __shfl_up(v, d);
        if (lane >= d) v += t;
    }
    if (lane == 63) wsum[wid] = v;
    __syncthreads();
    if (wid == 0 && lane < 4) {
        int s = wsum[lane];
        #pragma unroll
        for (int d = 1; d < 4; d <<= 1) {
            int t = __shfl_up(s, d);
            if (lane >= d) s += t;
        }
        wsum[lane] = s;
    }
    __syncthreads();
    if (wid > 0) v += wsum[wid - 1];
    return v;
}

__global__ __launch_bounds__(256) void k_bsum(const int* __restrict__ deg2, int* __restrict__ bsum, int n) {
    __shared__ int wsum[4];
    int i = blockIdx.x * 256 + threadIdx.x;
    int v = 0;
    if (i < n) v = deg2[i * 4] + deg2[i * 4 + 1] + deg2[i * 4 + 2] + deg2[i * 4 + 3];
    int lane = threadIdx.x & 63, wid = threadIdx.x >> 6;
    #pragma unroll
    for (int d = 32; d > 0; d >>= 1) v += __shfl_down(v, d);
    if (lane == 0) wsum[wid] = v;
    __syncthreads();
    if (threadIdx.x == 0) bsum[blockIdx.x] = wsum[0] + wsum[1] + wsum[2] + wsum[3];
}

// off[] + off2[]; base computed in-kernel: sum of bsum[0..b) (tiny, L2-broadcast)
__global__ __launch_bounds__(256) void k_off(const int* __restrict__ deg2, const int* __restrict__ bsum,
                                             int* __restrict__ off, int* __restrict__ off2, int n) {
    __shared__ int rsum[4];
    __shared__ int wsum[4];
    int tid = threadIdx.x;
    int b = blockIdx.x;
    int acc = 0;
    for (int i = tid; i < b; i += 256) acc += bsum[i];
    int lane = tid & 63, wid = tid >> 6;
    #pragma unroll
    for (int d = 32; d > 0; d >>= 1) acc += __shfl_xor(acc, d);
    if (lane == 0) rsum[wid] = acc;
    __syncthreads();
    int base = rsum[0] + rsum[1] + rsum[2] + rsum[3];
    int i = b * 256 + tid;
    int d0 = 0, d1 = 0, d2 = 0, d3 = 0;
    if (i < n) {
        d0 = deg2[i * 4]; d1 = deg2[i * 4 + 1]; d2 = deg2[i * 4 + 2]; d3 = deg2[i * 4 + 3];
    }
    int orig = d0 + d1 + d2 + d3;
    int v = block_incl_scan(orig, wsum);
    if (i < n) {
        int o = base + v - orig;
        off[i] = o;
        off2[i * 4]     = o;
        off2[i * 4 + 1] = o + d0;
        off2[i * 4 + 2] = o + d0 + d1;
        off2[i * 4 + 3] = o + d0 + d1 + d2;
    }
    if (i == n - 1) off[n] = base + v;
}

__global__ __launch_bounds__(256) void k_scatter(const int* __restrict__ ei, const int* __restrict__ off2,
                                                 const int* __restrict__ rank, int* __restrict__ csrc,
                                                 int E_, int N_) {
    int e = blockIdx.x * 256 + threadIdx.x;
    int total = E_ + N_;
    if (e >= total) return;
    int s, d;
    if (e < E_) { s = ei[e]; d = ei[E_ + e]; }
    else        { s = e - E_; d = e - E_; }
    csrc[off2[d * 4 + src_chunk(s)] + rank[e]] = s;
}

// Partition-fused: blocks [0,gatBlocks) = GAT layer-1 GEMM (identical body);
// blocks [gatBlocks,..) = per-(dst,chunk) histogram (identical body).
// No data overlap: gat reads xh/Wt3, writes hh/avs/avd; hist reads ei,
// atomics deg2, writes rank. Both depend only on k_zp.
__global__ __launch_bounds__(256, 3) void k_gat_hist(const _Float16* __restrict__ A16,
        const _Float16* __restrict__ Wt, const float* __restrict__ asrc, const float* __restrict__ adst,
        _Float16* __restrict__ hh, float* __restrict__ avs, float* __restrict__ avd, int M,
        const int* __restrict__ ei, int* __restrict__ deg2, int* __restrict__ rank,
        int E_, int N_, int gatBlocks) {
    __shared__ _Float16 As[64 * LDA];
    __shared__ _Float16 Bs[128 * LDA];
    int tid = threadIdx.x;
    if (blockIdx.x >= gatBlocks) {
        // ---- hist body ----
        int e = (blockIdx.x - gatBlocks) * 256 + tid;
        int total = E_ + N_;
        if (e >= total) return;
        int s, d;
        if (e < E_) { s = ei[e]; d = ei[E_ + e]; }
        else        { s = e - E_; d = e - E_; }
        rank[e] = atomicAdd(&deg2[d * 4 + src_chunk(s)], 1);
        return;
    }
    // ---- gat body (byte-identical to k_mfma_gat) ----
    int bm = blockIdx.x * 64;
    #pragma unroll
    for (int i = 0; i < 4; ++i) {
        int idx = i * 256 + tid;
        int row = idx >> 4, c16 = idx & 15;
        int gr = bm + row;
        uint4 v = make_uint4(0u, 0u, 0u, 0u);
        if (gr < M) v = *(const uint4*)(A16 + (size_t)gr * 128 + c16 * 8);
        *(uint4*)&As[row * LDA + c16 * 8] = v;
    }
    #pragma unroll
    for (int i = 0; i < 8; ++i) {
        int idx = i * 256 + tid;
        int row = idx >> 4, c16 = idx & 15;
        *(uint4*)&Bs[row * LDA + c16 * 8] = *(const uint4*)(Wt + (size_t)row * 128 + c16 * 8);
    }
    __syncthreads();
    int w = tid >> 6, l = tid & 63;
    int quad = l >> 4, cl = l & 15;
    f32x4 acc[8] = {};
    const _Float16* ap = &As[(w * 16 + cl) * LDA + quad * 8];
    #pragma unroll
    for (int kt = 0; kt < 4; ++kt) {
        half8 a = *(const half8*)(ap + kt * 32);
        #pragma unroll
        for (int ct = 0; ct < 8; ++ct) {
            half8 b = *(const half8*)&Bs[(ct * 16 + cl) * LDA + kt * 32 + quad * 8];
            acc[ct] = __builtin_amdgcn_mfma_f32_16x16x32_f16(a, b, acc[ct], 0, 0, 0);
        }
    }
    float sa[8], da[8];
    #pragma unroll
    for (int ct = 0; ct < 8; ++ct) { sa[ct] = asrc[ct * 16 + cl]; da[ct] = adst[ct * 16 + cl]; }
    #pragma unroll
    for (int r = 0; r < 4; ++r) {
        int row = bm + w * 16 + quad * 4 + r;
        bool ok = row < M;
        float ps = 0.f, pd = 0.f;
        #pragma unroll
        for (int ct = 0; ct < 8; ++ct) {
            float v = acc[ct][r];
            if (ok) hh[(size_t)row * 128 + ct * 16 + cl] = (_Float16)v;
            ps += v * sa[ct];
            pd += v * da[ct];
        }
        #pragma unroll
        for (int msk = 1; msk <= 8; msk <<= 1) { ps += __shfl_xor(ps, msk); pd += __shfl_xor(pd, msk); }
        if (cl == 0 && ok) { avs[row] = ps; avd[row] = pd; }
    }
}

// Layer GEMM via MFMA: hh[M x 128](fp16) = A16[M x 128] @ W + fused alpha dots.
__global__ __launch_bounds__(256, 3) void k_mfma_gat(const _Float16* __restrict__ A16,
        const _Float16* __restrict__ Wt, const float* __restrict__ asrc, const float* __restrict__ adst,
        _Float16* __restrict__ hh, float* __restrict__ avs, float* __restrict__ avd, int M) {
    __shared__ _Float16 As[64 * LDA];
    __shared__ _Float16 Bs[128 * LDA];
    int tid = threadIdx.x;
    int bm = blockIdx.x * 64;
    #pragma unroll
    for (int i = 0; i < 4; ++i) {
        int idx = i * 256 + tid;
        int row = idx >> 4, c16 = idx & 15;
        int gr = bm + row;
        uint4 v = make_uint4(0u, 0u, 0u, 0u);
        if (gr < M) v = *(const uint4*)(A16 + (size_t)gr * 128 + c16 * 8);
        *(uint4*)&As[row * LDA + c16 * 8] = v;
    }
    #pragma unroll
    for (int i = 0; i < 8; ++i) {
        int idx = i * 256 + tid;
        int row = idx >> 4, c16 = idx & 15;
        *(uint4*)&Bs[row * LDA + c16 * 8] = *(const uint4*)(Wt + (size_t)row * 128 + c16 * 8);
    }
    __syncthreads();
    int w = tid >> 6, l = tid & 63;
    int quad = l >> 4, cl = l & 15;
    f32x4 acc[8] = {};
    const _Float16* ap = &As[(w * 16 + cl) * LDA + quad * 8];
    #pragma unroll
    for (int kt = 0; kt < 4; ++kt) {
        half8 a = *(const half8*)(ap + kt * 32);
        #pragma unroll
        for (int ct = 0; ct < 8; ++ct) {
            half8 b = *(const half8*)&Bs[(ct * 16 + cl) * LDA + kt * 32 + quad * 8];
            acc[ct] = __builtin_amdgcn_mfma_f32_16x16x32_f16(a, b, acc[ct], 0, 0, 0);
        }
    }
    float sa[8], da[8];
    #pragma unroll
    for (int ct = 0; ct < 8; ++ct) { sa[ct] = asrc[ct * 16 + cl]; da[ct] = adst[ct * 16 + cl]; }
    #pragma unroll
    for (int r = 0; r < 4; ++r) {
        int row = bm + w * 16 + quad * 4 + r;
        bool ok = row < M;
        float ps = 0.f, pd = 0.f;
        #pragma unroll
        for (int ct = 0; ct < 8; ++ct) {
            float v = acc[ct][r];
            if (ok) hh[(size_t)row * 128 + ct * 16 + cl] = (_Float16)v;
            ps += v * sa[ct];
            pd += v * da[ct];
        }
        #pragma unroll
        for (int msk = 1; msk <= 8; msk <<= 1) { ps += __shfl_xor(ps, msk); pd += __shfl_xor(pd, msk); }
        if (cl == 0 && ok) { avs[row] = ps; avd[row] = pd; }
    }
}

// Fused MLP, acc[8]-only: out[M x 6] = relu(A16 @ Wm1 + bm1) @ Wm2 + bm2.
__global__ __launch_bounds__(256) void k_mfma_mlp(const _Float16* __restrict__ A16,
        const _Float16* __restrict__ Wt, const float* __restrict__ bias,
        const float* __restrict__ W2, const float* __restrict__ b2,
        float* __restrict__ out, int M) {
    __shared__ float W2s[256 * 6];
    __shared__ float bss[256];
    __shared__ float comb[4][16][6];
    int tid = threadIdx.x;
    #pragma unroll
    for (int i = 0; i < 6; ++i) W2s[i * 256 + tid] = W2[i * 256 + tid];
    bss[tid] = bias[tid];
    __syncthreads();
    int w = tid >> 6, l = tid & 63;
    int quad = l >> 4, cl = l & 15;
    int rg = w >> 1;             // row-group 0/1
    int ch = w & 1;              // col-half 0/1
    int bm = blockIdx.x * 32 + rg * 16;
    int arow = bm + cl;
    int arc = (arow < M) ? arow : (M - 1);   // clamp; combine discards OOB rows
    const _Float16* ap = A16 + (size_t)arc * 128 + quad * 8;
    f32x4 acc[8];
    #pragma unroll
    for (int i = 0; i < 8; ++i) acc[i] = (f32x4){0.f, 0.f, 0.f, 0.f};
    #pragma unroll
    for (int kt = 0; kt < 4; ++kt) {
        half8 av = *(const half8*)(ap + kt * 32);
        const _Float16* bp = Wt + (size_t)(ch * 128 + cl) * 128 + kt * 32 + quad * 8;
        #pragma unroll
        for (int ct = 0; ct < 8; ++ct) {
            half8 bv = *(const half8*)(bp + (size_t)ct * 16 * 128);
            acc[ct] = __builtin_amdgcn_mfma_f32_16x16x32_f16(av, bv, acc[ct], 0, 0, 0);
        }
    }
    float pc[4][6] = {};
    #pragma unroll
    for (int ct = 0; ct < 8; ++ct) {
        int col = ch * 128 + ct * 16 + cl;
        float bb = bss[col];
        float w0 = W2s[col * 6 + 0], w1 = W2s[col * 6 + 1], w2v = W2s[col * 6 + 2];
        float w3 = W2s[col * 6 + 3], w4 = W2s[col * 6 + 4], w5 = W2s[col * 6 + 5];
        #pragma unroll
        for (int r = 0; r < 4; ++r) {
            float v = fmaxf(acc[ct][r] + bb, 0.f);
            pc[r][0] += v * w0; pc[r][1] += v * w1; pc[r][2] += v * w2v;
            pc[r][3] += v * w3; pc[r][4] += v * w4; pc[r][5] += v * w5;
        }
    }
    #pragma unroll
    for (int r = 0; r < 4; ++r) {
        #pragma unroll
        for (int msk = 1; msk <= 8; msk <<= 1) {
            #pragma unroll
            for (int c = 0; c < 6; ++c) pc[r][c] += __shfl_xor(pc[r][c], msk);
        }
        if (cl == 0) {
            #pragma unroll
            for (int c = 0; c < 6; ++c) comb[w][quad * 4 + r][c] = pc[r][c];
        }
    }
    __syncthreads();
    // combine halves + store: 192 entries (2 row-groups x 16 rows x 6 cols)
    if (tid < 192) {
        int rgg = tid / 96;
        int rem = tid % 96;
        int rr = rem / 6, c = rem % 6;
        int row = blockIdx.x * 32 + rgg * 16 + rr;
        if (row < M)
            out[(size_t)row * 6 + c] = comb[rgg * 2][rr][c] + comb[rgg * 2 + 1][rr][c] + b2[c];
    }
}

// Group-owned aggregation: one 16-lane group per dst node (4 nodes/wave, 16/block).
__global__ __launch_bounds__(256) void k_aggregate(const _Float16* __restrict__ hh, const int* __restrict__ off,
                                                   const int* __restrict__ csrc, const float* __restrict__ avs,
                                                   const float* __restrict__ avd, const float* __restrict__ bias,
                                                   _Float16* __restrict__ outh, int n) {
    __shared__ float ew[16][DPAD];
    __shared__ int   si[16][DPAD];
    int tid = threadIdx.x;
    int row = tid >> 4;   // group slot 0..15
    int gl  = tid & 15;
    int w = blockIdx.x * 16 + row;
    if (w >= n) return;
    int beg = off[w], end = off[w + 1];
    int deg = end - beg;
    float adn = avd[w];
    float accf[8] = {};
    float ssum;

    if (deg <= DCAP) {
        // pass 1: scores -> LDS, group max, exp -> LDS, group sum
        float m = -1e30f;
        for (int k = gl; k < deg; k += 16) {
            int s = csrc[beg + k];
            float sc = avs[s] + adn;
            sc = (sc < 0.f) ? 0.2f * sc : sc;
            si[row][k] = s;
            ew[row][k] = sc;
            m = fmaxf(m, sc);
        }
        #pragma unroll
        for (int d = 1; d < 16; d <<= 1) m = fmaxf(m, __shfl_xor(m, d));
        float ss = 0.f;
        for (int k = gl; k < deg; k += 16) {
            float e = __expf(ew[row][k] - m);
            ew[row][k] = e;
            ss += e;
        }
        #pragma unroll
        for (int d = 1; d < 16; d <<= 1) ss += __shfl_xor(ss, d);
        ssum = ss;
        // pass 2: serial edges, 8-deep unroll; s/e broadcast from LDS
        int j = 0;
        for (; j + 7 < deg; j += 8) {
            int s0 = si[row][j],     s1 = si[row][j + 1], s2 = si[row][j + 2], s3 = si[row][j + 3];
            int s4 = si[row][j + 4], s5 = si[row][j + 5], s6 = si[row][j + 6], s7 = si[row][j + 7];
            half8 v0 = *((const half8*)(hh + (size_t)s0 * 128) + gl);
            half8 v1 = *((const half8*)(hh + (size_t)s1 * 128) + gl);
            half8 v2 = *((const half8*)(hh + (size_t)s2 * 128) + gl);
            half8 v3 = *((const half8*)(hh + (size_t)s3 * 128) + gl);
            half8 v4 = *((const half8*)(hh + (size_t)s4 * 128) + gl);
            half8 v5 = *((const half8*)(hh + (size_t)s5 * 128) + gl);
            half8 v6 = *((const half8*)(hh + (size_t)s6 * 128) + gl);
            half8 v7 = *((const half8*)(hh + (size_t)s7 * 128) + gl);
            float e0 = ew[row][j],     e1 = ew[row][j + 1], e2 = ew[row][j + 2], e3 = ew[row][j + 3];
            float e4 = ew[row][j + 4], e5 = ew[row][j + 5], e6 = ew[row][j + 6], e7 = ew[row][j + 7];
            #pragma unroll
            for (int f = 0; f < 8; ++f)
                accf[f] += ((e0 * (float)v0[f] + e1 * (float)v1[f])
                          + (e2 * (float)v2[f] + e3 * (float)v3[f]))
                         + ((e4 * (float)v4[f] + e5 * (float)v5[f])
                          + (e6 * (float)v6[f] + e7 * (float)v7[f]));
        }
        for (; j < deg; ++j) {
            int s0 = si[row][j];
            float e0 = ew[row][j];
            half8 v0 = *((const half8*)(hh + (size_t)s0 * 128) + gl);
            #pragma unroll
            for (int f = 0; f < 8; ++f) accf[f] += e0 * (float)v0[f];
        }
    } else {
        // online fallback (deg > DCAP): redundant per-lane scalar softmax
        float m = -1e30f;
        for (int k = gl; k < deg; k += 16) {
            float sc = avs[csrc[beg + k]] + adn;
            sc = (sc < 0.f) ? 0.2f * sc : sc;
            m = fmaxf(m, sc);
        }
        #pragma unroll
        for (int d = 1; d < 16; d <<= 1) m = fmaxf(m, __shfl_xor(m, d));
        float ss = 0.f;
        for (int j = beg; j < end; ++j) {
            int s = csrc[j];
            float sc = avs[s] + adn;
            sc = (sc < 0.f) ? 0.2f * sc : sc;
            float e0 = __expf(sc - m);
            ss += e0;
            half8 v0 = *((const half8*)(hh + (size_t)s * 128) + gl);
            #pragma unroll
            for (int f = 0; f < 8; ++f) accf[f] += e0 * (float)v0[f];
        }
        ssum = ss;
    }
    float inv = 1.f / ssum;
    float4 b0 = ((const float4*)bias)[gl * 2];
    float4 b1 = ((const float4*)bias)[gl * 2 + 1];
    half8 o;
    o[0] = (_Float16)fmaxf(accf[0] * inv + b0.x, 0.f);
    o[1] = (_Float16)fmaxf(accf[1] * inv + b0.y, 0.f);
    o[2] = (_Float16)fmaxf(accf[2] * inv + b0.z, 0.f);
    o[3] = (_Float16)fmaxf(accf[3] * inv + b0.w, 0.f);
    o[4] = (_Float16)fmaxf(accf[4] * inv + b1.x, 0.f);
    o[5] = (_Float16)fmaxf(accf[5] * inv + b1.y, 0.f);
    o[6] = (_Float16)fmaxf(accf[6] * inv + b1.z, 0.f);
    o[7] = (_Float16)fmaxf(accf[7] * inv + b1.w, 0.f);
    *((half8*)(outh + (size_t)w * 128) + gl) = o;
}

extern "C" void kernel_launch(void* const* d_in, const int* in_sizes, int n_in,
                              void* d_out, int out_size, void* d_ws, size_t ws_size,
                              hipStream_t stream) {
    const float* x   = (const float*)d_in[0];
    const int*   ei  = (const int*)d_in[1];
    const float* W[3]    = {(const float*)d_in[2], (const float*)d_in[6], (const float*)d_in[10]};
    const float* bL[3]   = {(const float*)d_in[3], (const float*)d_in[7], (const float*)d_in[11]};
    const float* asr[3]  = {(const float*)d_in[4], (const float*)d_in[8], (const float*)d_in[12]};
    const float* ads[3]  = {(const float*)d_in[5], (const float*)d_in[9], (const float*)d_in[13]};
    const float* Wm1 = (const float*)d_in[14];
    const float* bm1 = (const float*)d_in[15];
    const float* Wm2 = (const float*)d_in[16];
    const float* bm2 = (const float*)d_in[17];
    float* out = (float*)d_out;

    const int N_ = in_sizes[0] / 128;
    const int E_ = in_sizes[1] / 2;
    const int TOT = E_ + N_;
    const int NB = (N_ + 255) / 256;

    char* p = (char*)d_ws;
    auto alloc = [&](size_t bytes) { void* r = (void*)p; p += (bytes + 255) & ~(size_t)255; return r; };
    int*   deg2 = (int*)alloc((size_t)N_ * 4 * 4);
    int*   off  = (int*)alloc((size_t)(N_ + 1) * 4);
    int*   off2 = (int*)alloc((size_t)N_ * 4 * 4);
    int*   bsum = (int*)alloc((size_t)(NB + 1) * 4);
    int*   rank = (int*)alloc((size_t)TOT * 4);
    int*   csrc = (int*)alloc((size_t)TOT * 4);
    float* avs  = (float*)alloc((size_t)N_ * 4);
    float* avd  = (float*)alloc((size_t)N_ * 4);
    _Float16* Wt3  = (_Float16*)alloc(3 * 16384 * 2);
    _Float16* Wm1t = (_Float16*)alloc(32768 * 2);
    _Float16* xh   = (_Float16*)alloc((size_t)N_ * 128 * 2);
    _Float16* agg  = (_Float16*)alloc((size_t)N_ * 128 * 2);
    _Float16* hh   = (_Float16*)alloc((size_t)N_ * 128 * 2);

    const int agg_blocks = (N_ + 15) / 16;
    const int gat_blocks = (N_ + 63) / 64;
    const int hist_blocks = (TOT + 255) / 256;

    // ---- fused CSR build (chunk-ordered) + prep ----
    int nz = N_ * 4;
    int n4 = N_ * 32;
    int zp_items = nz + n4 + 3 * 16384 + 32768;
    k_zp<<<(zp_items + 255) / 256, 256, 0, stream>>>(deg2, nz, x, xh, W[0], W[1], W[2],
                                                     Wt3, Wm1, Wm1t, n4);
    // gat layer 1 + hist fused (both depend only on k_zp)
    k_gat_hist<<<gat_blocks + hist_blocks, 256, 0, stream>>>(xh, Wt3, asr[0], ads[0],
                                                             hh, avs, avd, N_,
                                                             ei, deg2, rank, E_, N_, gat_blocks);
    k_bsum<<<NB, 256, 0, stream>>>(deg2, bsum, N_);
    k_off<<<NB, 256, 0, stream>>>(deg2, bsum, off, off2, N_);
    k_scatter<<<(TOT + 255) / 256, 256, 0, stream>>>(ei, off2, rank, csrc, E_, N_);

    // ---- layer 1 aggregate, then layers 2-3 ----
    k_aggregate<<<agg_blocks, 256, 0, stream>>>(hh, off, csrc, avs, avd, bL[0], agg, N_);
    const _Float16* cur_in = agg;
    for (int l = 1; l < 3; ++l) {
        k_mfma_gat<<<gat_blocks, 256, 0, stream>>>(cur_in, Wt3 + l * 16384, asr[l], ads[l],
                                                   hh, avs, avd, N_);
        k_aggregate<<<agg_blocks, 256, 0, stream>>>(hh, off, csrc, avs, avd, bL[l], agg, N_);
        cur_in = agg;
    }

    // ---- fused MLP head ----
    k_mfma_mlp<<<(N_ + 31) / 32, 256, 0, stream>>>(agg, Wm1t, bm1, Wm2, bm2, out, N_);
}